// Round 1
// baseline (1416.482 us; speedup 1.0000x reference)
//
#include <hip/hip_runtime.h>

#define MDIM 8192
#define NDIM 16384
#define KDIM 4096

typedef __bf16 bf16x8 __attribute__((ext_vector_type(8)));
typedef float f32x4 __attribute__((ext_vector_type(4)));

__device__ __forceinline__ unsigned short f2bf(float f) {
  __bf16 h = (__bf16)f;
  return __builtin_bit_cast(unsigned short, h);
}

__device__ __forceinline__ void gload_lds16(const void* g, void* l) {
  __builtin_amdgcn_global_load_lds(
      (const __attribute__((address_space(1))) unsigned int*)g,
      (__attribute__((address_space(3))) unsigned int*)l, 16, 0, 0);
}

// ---------- pass 1a: fp32 -> bf16 ----------
__global__ __launch_bounds__(256) void cvt_a_kernel(const float* __restrict__ a,
                                                    unsigned short* __restrict__ o,
                                                    long long n) {
  long long i = ((long long)blockIdx.x * 256 + threadIdx.x) * 8;
  const long long stride = (long long)gridDim.x * 2048;
  for (; i < n; i += stride) {
    float4 x = *(const float4*)(a + i);
    float4 y = *(const float4*)(a + i + 4);
    union { unsigned short u[8]; uint4 v; } r;
    r.u[0] = f2bf(x.x); r.u[1] = f2bf(x.y); r.u[2] = f2bf(x.z); r.u[3] = f2bf(x.w);
    r.u[4] = f2bf(y.x); r.u[5] = f2bf(y.y); r.u[6] = f2bf(y.z); r.u[7] = f2bf(y.w);
    *(uint4*)(o + i) = r.v;
  }
}

// ---------- pass 1b: int32 (int8 values) -> bf16 (exact, |w|<=127) ----------
__global__ __launch_bounds__(256) void cvt_w_kernel(const int* __restrict__ w,
                                                    unsigned short* __restrict__ o,
                                                    long long n) {
  long long i = ((long long)blockIdx.x * 256 + threadIdx.x) * 8;
  const long long stride = (long long)gridDim.x * 2048;
  for (; i < n; i += stride) {
    int4 x = *(const int4*)(w + i);
    int4 y = *(const int4*)(w + i + 4);
    union { unsigned short u[8]; uint4 v; } r;
    r.u[0] = f2bf((float)x.x); r.u[1] = f2bf((float)x.y);
    r.u[2] = f2bf((float)x.z); r.u[3] = f2bf((float)x.w);
    r.u[4] = f2bf((float)y.x); r.u[5] = f2bf((float)y.y);
    r.u[6] = f2bf((float)y.z); r.u[7] = f2bf((float)y.w);
    *(uint4*)(o + i) = r.v;
  }
}

// ---------- pass 2: bf16 GEMM, m97 structure (128x128 tile, BK=64, gl_lds w16,
//            XOR-swizzled LDS via pre-swizzled global source, fused scale/bias) --
__global__ __launch_bounds__(256, 3) void gemm_bf16_ws(
    const unsigned short* __restrict__ Ab, const unsigned short* __restrict__ Wb,
    const float* __restrict__ sc, const float* __restrict__ bi,
    float* __restrict__ out) {
  __shared__ unsigned short As[8192];  // [128 rows][64 k] bf16, linear (gl_lds dest)
  __shared__ unsigned short Bs[8192];
  const int tid = threadIdx.x;
  const int lane = tid & 63;
  const int wv = tid >> 6;
  // XCD-aware bijective swizzle: 8192 blocks, 8 XCDs
  const int wg = (blockIdx.x & 7) * 1024 + (blockIdx.x >> 3);
  const int bm = (wg & 63) * 128;   // M/128 = 64, consecutive wg share B-panel
  const int bn = (wg >> 6) * 128;   // N/128 = 128
  const int wr = (wv >> 1) * 64;
  const int wc = (wv & 1) * 64;
  const int r16 = lane & 15;
  const int g4 = lane >> 4;
  const int swz = (lane & 7) << 3;  // frag-read XOR (elems); row&7 == lane&7

  f32x4 acc[4][4] = {};

  // staging: wave w fills chunks c=4w..4w+3 (1 KiB each = 8 rows x 64 k bf16).
  // gl_lds writes linear (base + lane*16B); source is pre-swizzled so that a
  // swizzled ds_read (byte ^= (row&7)<<4) recovers the true (row,k) data.
  const int srow = lane >> 3;
  const int scol = ((lane & 7) ^ srow) << 3;
  const unsigned short* aP[4];
  const unsigned short* bP[4];
  unsigned short* aD[4];
  unsigned short* bD[4];
#pragma unroll
  for (int j = 0; j < 4; ++j) {
    const int c = wv * 4 + j;
    aP[j] = Ab + (long long)(bm + c * 8 + srow) * KDIM + scol;
    bP[j] = Wb + (long long)(bn + c * 8 + srow) * KDIM + scol;
    aD[j] = &As[c * 512];
    bD[j] = &Bs[c * 512];
  }

  for (int kt = 0; kt < KDIM; kt += 64) {
#pragma unroll
    for (int j = 0; j < 4; ++j) {
      gload_lds16(aP[j], aD[j]);
      gload_lds16(bP[j], bD[j]);
      aP[j] += 64;
      bP[j] += 64;
    }
    __syncthreads();  // drains vmcnt (compiler) -> tiles resident
#pragma unroll
    for (int ks = 0; ks < 2; ++ks) {
      bf16x8 aF[4], bF[4];
      const int kofs = ks * 32 + g4 * 8;
#pragma unroll
      for (int m2 = 0; m2 < 4; ++m2)
        aF[m2] = *(const bf16x8*)&As[(wr + m2 * 16 + r16) * 64 + (kofs ^ swz)];
#pragma unroll
      for (int n2 = 0; n2 < 4; ++n2)
        bF[n2] = *(const bf16x8*)&Bs[(wc + n2 * 16 + r16) * 64 + (kofs ^ swz)];
#pragma unroll
      for (int m2 = 0; m2 < 4; ++m2)
#pragma unroll
        for (int n2 = 0; n2 < 4; ++n2)
          acc[m2][n2] = __builtin_amdgcn_mfma_f32_16x16x32_bf16(
              aF[m2], bF[n2], acc[m2][n2], 0, 0, 0);
    }
    __syncthreads();
  }

  // epilogue: C/D layout col = lane&15, row = (lane>>4)*4 + r (m89-verified)
  float sv[4], bv[4];
#pragma unroll
  for (int n2 = 0; n2 < 4; ++n2) {
    const int c = bn + wc + n2 * 16 + r16;
    sv[n2] = sc[c];
    bv[n2] = bi[c];
  }
#pragma unroll
  for (int m2 = 0; m2 < 4; ++m2) {
    const int row0 = bm + wr + m2 * 16 + g4 * 4;
#pragma unroll
    for (int n2 = 0; n2 < 4; ++n2) {
      const int c = bn + wc + n2 * 16 + r16;
      float* op = out + (long long)row0 * NDIM + c;
#pragma unroll
      for (int r = 0; r < 4; ++r)
        op[(long long)r * NDIM] = acc[m2][n2][r] * sv[n2] + bv[n2];
    }
  }
}

// ---------- fallback: inline-convert reg-staged GEMM (if ws too small) ----------
__global__ __launch_bounds__(256, 2) void gemm_inline(
    const float* __restrict__ A, const int* __restrict__ W,
    const float* __restrict__ sc, const float* __restrict__ bi,
    float* __restrict__ out) {
  __shared__ unsigned short As[128 * 72];  // +8 pad -> 2-way banks (free, m136)
  __shared__ unsigned short Bs[128 * 72];
  const int tid = threadIdx.x;
  const int lane = tid & 63;
  const int wv = tid >> 6;
  const int wg = (blockIdx.x & 7) * 1024 + (blockIdx.x >> 3);
  const int bm = (wg & 63) * 128;
  const int bn = (wg >> 6) * 128;
  const int wr = (wv >> 1) * 64;
  const int wc = (wv & 1) * 64;
  const int r16 = lane & 15;
  const int g4 = lane >> 4;

  f32x4 acc[4][4] = {};

  const int srow = tid >> 4;        // 0..15 (j adds 16 per step)
  const int sc4 = (tid & 15) << 2;  // 0..60
  const float* aPtr = A + (long long)(bm + srow) * KDIM + sc4;
  const int* wPtr = W + (long long)(bn + srow) * KDIM + sc4;

  for (int kt = 0; kt < KDIM; kt += 64) {
    float4 av[8];
    int4 wv4[8];
#pragma unroll
    for (int j = 0; j < 8; ++j)
      av[j] = *(const float4*)(aPtr + (long long)j * 16 * KDIM + kt);
#pragma unroll
    for (int j = 0; j < 8; ++j)
      wv4[j] = *(const int4*)(wPtr + (long long)j * 16 * KDIM + kt);
    __syncthreads();  // all waves done reading prev tile
#pragma unroll
    for (int j = 0; j < 8; ++j) {
      ushort4 u;
      u.x = f2bf(av[j].x); u.y = f2bf(av[j].y);
      u.z = f2bf(av[j].z); u.w = f2bf(av[j].w);
      *(ushort4*)&As[(srow + j * 16) * 72 + sc4] = u;
    }
#pragma unroll
    for (int j = 0; j < 8; ++j) {
      ushort4 u;
      u.x = f2bf((float)wv4[j].x); u.y = f2bf((float)wv4[j].y);
      u.z = f2bf((float)wv4[j].z); u.w = f2bf((float)wv4[j].w);
      *(ushort4*)&Bs[(srow + j * 16) * 72 + sc4] = u;
    }
    __syncthreads();
#pragma unroll
    for (int ks = 0; ks < 2; ++ks) {
      bf16x8 aF[4], bF[4];
      const int kofs = ks * 32 + g4 * 8;
#pragma unroll
      for (int m2 = 0; m2 < 4; ++m2)
        aF[m2] = *(const bf16x8*)&As[(wr + m2 * 16 + r16) * 72 + kofs];
#pragma unroll
      for (int n2 = 0; n2 < 4; ++n2)
        bF[n2] = *(const bf16x8*)&Bs[(wc + n2 * 16 + r16) * 72 + kofs];
#pragma unroll
      for (int m2 = 0; m2 < 4; ++m2)
#pragma unroll
        for (int n2 = 0; n2 < 4; ++n2)
          acc[m2][n2] = __builtin_amdgcn_mfma_f32_16x16x32_bf16(
              aF[m2], bF[n2], acc[m2][n2], 0, 0, 0);
    }
  }

  float sv[4], bv[4];
#pragma unroll
  for (int n2 = 0; n2 < 4; ++n2) {
    const int c = bn + wc + n2 * 16 + r16;
    sv[n2] = sc[c];
    bv[n2] = bi[c];
  }
#pragma unroll
  for (int m2 = 0; m2 < 4; ++m2) {
    const int row0 = bm + wr + m2 * 16 + g4 * 4;
#pragma unroll
    for (int n2 = 0; n2 < 4; ++n2) {
      const int c = bn + wc + n2 * 16 + r16;
      float* op = out + (long long)row0 * NDIM + c;
#pragma unroll
      for (int r = 0; r < 4; ++r)
        op[(long long)r * NDIM] = acc[m2][n2][r] * sv[n2] + bv[n2];
    }
  }
}

extern "C" void kernel_launch(void* const* d_in, const int* in_sizes, int n_in,
                              void* d_out, int out_size, void* d_ws, size_t ws_size,
                              hipStream_t stream) {
  const float* A = (const float*)d_in[0];
  const int* W = (const int*)d_in[1];  // int8 values stored as int32 per harness contract
  const float* sc = (const float*)d_in[2];
  const float* bi = (const float*)d_in[3];
  float* out = (float*)d_out;

  const long long nA = (long long)MDIM * KDIM;
  const long long nW = (long long)NDIM * KDIM;
  const size_t needA = (size_t)nA * sizeof(unsigned short);
  const size_t needW = (size_t)nW * sizeof(unsigned short);

  if (d_ws != nullptr && ws_size >= needA + needW) {
    unsigned short* Ab = (unsigned short*)d_ws;
    unsigned short* Wb = (unsigned short*)((char*)d_ws + needA);
    cvt_a_kernel<<<2048, 256, 0, stream>>>(A, Ab, nA);
    cvt_w_kernel<<<4096, 256, 0, stream>>>(W, Wb, nW);
    gemm_bf16_ws<<<8192, 256, 0, stream>>>(Ab, Wb, sc, bi, out);
  } else {
    gemm_inline<<<8192, 256, 0, stream>>>(A, W, sc, bi, out);
  }
}

// Round 2
// 1311.790 us; speedup vs baseline: 1.0798x; 1.0798x over previous
//
#include <hip/hip_runtime.h>

#define MDIM 8192
#define NDIM 16384
#define KDIM 4096

typedef __bf16 bf16x8 __attribute__((ext_vector_type(8)));
typedef float f32x4 __attribute__((ext_vector_type(4)));

__device__ __forceinline__ unsigned short f2bf(float f) {
  __bf16 h = (__bf16)f;
  return __builtin_bit_cast(unsigned short, h);
}

__device__ __forceinline__ void gload_lds16(const void* g, void* l) {
  __builtin_amdgcn_global_load_lds(
      (const __attribute__((address_space(1))) unsigned int*)g,
      (__attribute__((address_space(3))) unsigned int*)l, 16, 0, 0);
}

// ---------- pass 1a: fp32 -> bf16 ----------
__global__ __launch_bounds__(256) void cvt_a_kernel(const float* __restrict__ a,
                                                    unsigned short* __restrict__ o,
                                                    long long n) {
  long long i = ((long long)blockIdx.x * 256 + threadIdx.x) * 8;
  const long long stride = (long long)gridDim.x * 2048;
  for (; i < n; i += stride) {
    float4 x = *(const float4*)(a + i);
    float4 y = *(const float4*)(a + i + 4);
    union { unsigned short u[8]; uint4 v; } r;
    r.u[0] = f2bf(x.x); r.u[1] = f2bf(x.y); r.u[2] = f2bf(x.z); r.u[3] = f2bf(x.w);
    r.u[4] = f2bf(y.x); r.u[5] = f2bf(y.y); r.u[6] = f2bf(y.z); r.u[7] = f2bf(y.w);
    *(uint4*)(o + i) = r.v;
  }
}

// ---------- pass 1b: int32 (int8 values) -> bf16 (exact, |w|<=127) ----------
__global__ __launch_bounds__(256) void cvt_w_kernel(const int* __restrict__ w,
                                                    unsigned short* __restrict__ o,
                                                    long long n) {
  long long i = ((long long)blockIdx.x * 256 + threadIdx.x) * 8;
  const long long stride = (long long)gridDim.x * 2048;
  for (; i < n; i += stride) {
    int4 x = *(const int4*)(w + i);
    int4 y = *(const int4*)(w + i + 4);
    union { unsigned short u[8]; uint4 v; } r;
    r.u[0] = f2bf((float)x.x); r.u[1] = f2bf((float)x.y);
    r.u[2] = f2bf((float)x.z); r.u[3] = f2bf((float)x.w);
    r.u[4] = f2bf((float)y.x); r.u[5] = f2bf((float)y.y);
    r.u[6] = f2bf((float)y.z); r.u[7] = f2bf((float)y.w);
    *(uint4*)(o + i) = r.v;
  }
}

// ---------- pass 2: 256x256 tile, BK=32, 4-buffer counted-vmcnt pipeline ------
// 8 waves (2M x 4N), each computes 128x64 via 8x4 mfma_16x16x32_bf16.
// LDS: 4 bufs x (A 16KiB + B 16KiB) = 128 KiB. Pipeline 3 tiles deep:
//   iter t: issue stage(t+3) -> buf (t+3)&3 (== (t-1)&3, freed by iter-t-1
//   barrier); ds_read tile t; 32 MFMA; s_waitcnt vmcnt(8)  [tile t+1 landed,
//   t+2/t+3 still in flight]; raw s_barrier.  vmcnt never drains to 0 in loop.
// Swizzle: 16B slot within each 64B row XOR'd by (row>>1)&3 -> uniform
// 8 words/bank on ds_read_b128; inverse applied to the per-lane GLOBAL source
// (gl_lds LDS dest must stay linear).
__global__ __launch_bounds__(512, 2) void gemm_bf16_pipe(
    const unsigned short* __restrict__ Ab, const unsigned short* __restrict__ Wb,
    const float* __restrict__ sc, const float* __restrict__ bi,
    float* __restrict__ out) {
  __shared__ unsigned short sm[4][2][8192];  // [buf][A/B][256 rows x 32 k]
  const int tid = threadIdx.x;
  const int lane = tid & 63;
  const int wv = tid >> 6;
  // XCD-aware swizzle: 2048 blocks % 8 == 0
  const int wg = (blockIdx.x & 7) * 256 + (blockIdx.x >> 3);
  const int bm = (wg & 31) * 256;  // M/256 = 32; consecutive wg share B-panel
  const int bn = (wg >> 5) * 256;  // N/256 = 64
  const int wr = wv >> 2;          // 0..1 -> rows wr*128..+128
  const int wc = wv & 3;           // 0..3 -> cols wc*64..+64
  const int r16 = lane & 15;
  const int g4 = lane >> 4;

  // staging source (pre-swizzled k-slot so swizzled ds_read recovers (row,k)):
  // thread t covers LDS bytes t*16 of each 8KiB step -> row = step*128 + t/4,
  // phys slot = t&3, logical kslot = (t&3) ^ ((t>>3)&3)  [(row>>1)&3 == (t>>3)&3]
  const int ksl8 = (((tid & 3) ^ ((tid >> 3) & 3)) << 3);
  const unsigned short* aSrc = Ab + (long long)(bm + (tid >> 2)) * KDIM + ksl8;
  const unsigned short* bSrc = Wb + (long long)(bn + (tid >> 2)) * KDIM + ksl8;

  // tile-invariant swizzled frag offsets (ushort units)
  int aOff[8], bOff[4];
#pragma unroll
  for (int m = 0; m < 8; ++m) {
    const int row = wr * 128 + m * 16 + r16;
    aOff[m] = row * 32 + ((g4 ^ ((row >> 1) & 3)) << 3);
  }
#pragma unroll
  for (int n = 0; n < 4; ++n) {
    const int row = wc * 64 + n * 16 + r16;
    bOff[n] = row * 32 + ((g4 ^ ((row >> 1) & 3)) << 3);
  }

  f32x4 acc[8][4] = {};

  auto STAGE = [&](int buf, int kt) {
    const unsigned short* a0 = aSrc + kt;
    const unsigned short* b0 = bSrc + kt;
    gload_lds16(a0, &sm[buf][0][wv * 512]);
    gload_lds16(a0 + 128 * KDIM, &sm[buf][0][4096 + wv * 512]);
    gload_lds16(b0, &sm[buf][1][wv * 512]);
    gload_lds16(b0 + 128 * KDIM, &sm[buf][1][4096 + wv * 512]);
  };

  // prologue: 3 tiles in flight, wait oldest (tile 0)
  STAGE(0, 0);
  STAGE(1, 32);
  STAGE(2, 64);
  asm volatile("s_waitcnt vmcnt(8)" ::: "memory");
  asm volatile("s_barrier" ::: "memory");

  for (int t = 0; t < 128; ++t) {
    if (t < 125) STAGE((t + 3) & 3, (t + 3) * 32);
    const unsigned short* Al = &sm[t & 3][0][0];
    const unsigned short* Bl = &sm[t & 3][1][0];
    bf16x8 aF[8], bF[4];
#pragma unroll
    for (int m = 0; m < 8; ++m) aF[m] = *(const bf16x8*)&Al[aOff[m]];
#pragma unroll
    for (int n = 0; n < 4; ++n) bF[n] = *(const bf16x8*)&Bl[bOff[n]];
    __builtin_amdgcn_s_setprio(1);
#pragma unroll
    for (int m = 0; m < 8; ++m)
#pragma unroll
      for (int n = 0; n < 4; ++n)
        acc[m][n] = __builtin_amdgcn_mfma_f32_16x16x32_bf16(
            aF[m], bF[n], acc[m][n], 0, 0, 0);
    __builtin_amdgcn_s_setprio(0);
    if (t < 125) {
      asm volatile("s_waitcnt vmcnt(8)" ::: "memory");  // tile t+1 landed
    } else if (t == 125) {
      asm volatile("s_waitcnt vmcnt(4)" ::: "memory");
    } else if (t == 126) {
      asm volatile("s_waitcnt vmcnt(0)" ::: "memory");
    }
    if (t < 127) asm volatile("s_barrier" ::: "memory");
  }

  // epilogue: C/D layout col = lane&15, row = (lane>>4)*4 + r
  float sv[4], bv[4];
#pragma unroll
  for (int n = 0; n < 4; ++n) {
    const int c = bn + wc * 64 + n * 16 + r16;
    sv[n] = sc[c];
    bv[n] = bi[c];
  }
#pragma unroll
  for (int m = 0; m < 8; ++m) {
    const int row0 = bm + wr * 128 + m * 16 + g4 * 4;
#pragma unroll
    for (int n = 0; n < 4; ++n) {
      const int c = bn + wc * 64 + n * 16 + r16;
      float* op = out + (long long)row0 * NDIM + c;
#pragma unroll
      for (int r = 0; r < 4; ++r)
        op[(long long)r * NDIM] = acc[m][n][r] * sv[n] + bv[n];
    }
  }
}

// ---------- fallback: inline-convert reg-staged GEMM (if ws too small) ----------
__global__ __launch_bounds__(256, 2) void gemm_inline(
    const float* __restrict__ A, const int* __restrict__ W,
    const float* __restrict__ sc, const float* __restrict__ bi,
    float* __restrict__ out) {
  __shared__ unsigned short As[128 * 72];
  __shared__ unsigned short Bs[128 * 72];
  const int tid = threadIdx.x;
  const int lane = tid & 63;
  const int wv = tid >> 6;
  const int wg = (blockIdx.x & 7) * 1024 + (blockIdx.x >> 3);
  const int bm = (wg & 63) * 128;
  const int bn = (wg >> 6) * 128;
  const int wr = (wv >> 1) * 64;
  const int wc = (wv & 1) * 64;
  const int r16 = lane & 15;
  const int g4 = lane >> 4;

  f32x4 acc[4][4] = {};

  const int srow = tid >> 4;
  const int sc4 = (tid & 15) << 2;
  const float* aPtr = A + (long long)(bm + srow) * KDIM + sc4;
  const int* wPtr = W + (long long)(bn + srow) * KDIM + sc4;

  for (int kt = 0; kt < KDIM; kt += 64) {
    float4 av[8];
    int4 wv4[8];
#pragma unroll
    for (int j = 0; j < 8; ++j)
      av[j] = *(const float4*)(aPtr + (long long)j * 16 * KDIM + kt);
#pragma unroll
    for (int j = 0; j < 8; ++j)
      wv4[j] = *(const int4*)(wPtr + (long long)j * 16 * KDIM + kt);
    __syncthreads();
#pragma unroll
    for (int j = 0; j < 8; ++j) {
      ushort4 u;
      u.x = f2bf(av[j].x); u.y = f2bf(av[j].y);
      u.z = f2bf(av[j].z); u.w = f2bf(av[j].w);
      *(ushort4*)&As[(srow + j * 16) * 72 + sc4] = u;
    }
#pragma unroll
    for (int j = 0; j < 8; ++j) {
      ushort4 u;
      u.x = f2bf((float)wv4[j].x); u.y = f2bf((float)wv4[j].y);
      u.z = f2bf((float)wv4[j].z); u.w = f2bf((float)wv4[j].w);
      *(ushort4*)&Bs[(srow + j * 16) * 72 + sc4] = u;
    }
    __syncthreads();
#pragma unroll
    for (int ks = 0; ks < 2; ++ks) {
      bf16x8 aF[4], bF[4];
      const int kofs = ks * 32 + g4 * 8;
#pragma unroll
      for (int m2 = 0; m2 < 4; ++m2)
        aF[m2] = *(const bf16x8*)&As[(wr + m2 * 16 + r16) * 72 + kofs];
#pragma unroll
      for (int n2 = 0; n2 < 4; ++n2)
        bF[n2] = *(const bf16x8*)&Bs[(wc + n2 * 16 + r16) * 72 + kofs];
#pragma unroll
      for (int m2 = 0; m2 < 4; ++m2)
#pragma unroll
        for (int n2 = 0; n2 < 4; ++n2)
          acc[m2][n2] = __builtin_amdgcn_mfma_f32_16x16x32_bf16(
              aF[m2], bF[n2], acc[m2][n2], 0, 0, 0);
    }
  }

  float sv[4], bv[4];
#pragma unroll
  for (int n2 = 0; n2 < 4; ++n2) {
    const int c = bn + wc + n2 * 16 + r16;
    sv[n2] = sc[c];
    bv[n2] = bi[c];
  }
#pragma unroll
  for (int m2 = 0; m2 < 4; ++m2) {
    const int row0 = bm + wr + m2 * 16 + g4 * 4;
#pragma unroll
    for (int n2 = 0; n2 < 4; ++n2) {
      const int c = bn + wc + n2 * 16 + r16;
      float* op = out + (long long)row0 * NDIM + c;
#pragma unroll
      for (int r = 0; r < 4; ++r)
        op[(long long)r * NDIM] = acc[m2][n2][r] * sv[n2] + bv[n2];
    }
  }
}

extern "C" void kernel_launch(void* const* d_in, const int* in_sizes, int n_in,
                              void* d_out, int out_size, void* d_ws, size_t ws_size,
                              hipStream_t stream) {
  const float* A = (const float*)d_in[0];
  const int* W = (const int*)d_in[1];
  const float* sc = (const float*)d_in[2];
  const float* bi = (const float*)d_in[3];
  float* out = (float*)d_out;

  const long long nA = (long long)MDIM * KDIM;
  const long long nW = (long long)NDIM * KDIM;
  const size_t needA = (size_t)nA * sizeof(unsigned short);
  const size_t needW = (size_t)nW * sizeof(unsigned short);

  if (d_ws != nullptr && ws_size >= needA + needW) {
    unsigned short* Ab = (unsigned short*)d_ws;
    unsigned short* Wb = (unsigned short*)((char*)d_ws + needA);
    cvt_a_kernel<<<2048, 256, 0, stream>>>(A, Ab, nA);
    cvt_w_kernel<<<4096, 256, 0, stream>>>(W, Wb, nW);
    gemm_bf16_pipe<<<2048, 512, 0, stream>>>(Ab, Wb, sc, bi, out);
  } else {
    gemm_inline<<<8192, 256, 0, stream>>>(A, W, sc, bi, out);
  }
}

// Round 3
// 1283.050 us; speedup vs baseline: 1.1040x; 1.0224x over previous
//
#include <hip/hip_runtime.h>

#define MDIM 8192
#define NDIM 16384
#define KDIM 4096

typedef __bf16 bf16x8 __attribute__((ext_vector_type(8)));
typedef float f32x4 __attribute__((ext_vector_type(4)));

__device__ __forceinline__ unsigned short f2bf(float f) {
  __bf16 h = (__bf16)f;
  return __builtin_bit_cast(unsigned short, h);
}

__device__ __forceinline__ void gload_lds16(const void* g, void* l) {
  __builtin_amdgcn_global_load_lds(
      (const __attribute__((address_space(1))) unsigned int*)g,
      (__attribute__((address_space(3))) unsigned int*)l, 16, 0, 0);
}

// ---------- pass 1a: fp32 -> bf16 ----------
__global__ __launch_bounds__(256) void cvt_a_kernel(const float* __restrict__ a,
                                                    unsigned short* __restrict__ o,
                                                    long long n) {
  long long i = ((long long)blockIdx.x * 256 + threadIdx.x) * 8;
  const long long stride = (long long)gridDim.x * 2048;
  for (; i < n; i += stride) {
    float4 x = *(const float4*)(a + i);
    float4 y = *(const float4*)(a + i + 4);
    union { unsigned short u[8]; uint4 v; } r;
    r.u[0] = f2bf(x.x); r.u[1] = f2bf(x.y); r.u[2] = f2bf(x.z); r.u[3] = f2bf(x.w);
    r.u[4] = f2bf(y.x); r.u[5] = f2bf(y.y); r.u[6] = f2bf(y.z); r.u[7] = f2bf(y.w);
    *(uint4*)(o + i) = r.v;
  }
}

// ---------- pass 1b: int32 (int8 values) -> bf16 (exact, |w|<=127) ----------
__global__ __launch_bounds__(256) void cvt_w_kernel(const int* __restrict__ w,
                                                    unsigned short* __restrict__ o,
                                                    long long n) {
  long long i = ((long long)blockIdx.x * 256 + threadIdx.x) * 8;
  const long long stride = (long long)gridDim.x * 2048;
  for (; i < n; i += stride) {
    int4 x = *(const int4*)(w + i);
    int4 y = *(const int4*)(w + i + 4);
    union { unsigned short u[8]; uint4 v; } r;
    r.u[0] = f2bf((float)x.x); r.u[1] = f2bf((float)x.y);
    r.u[2] = f2bf((float)x.z); r.u[3] = f2bf((float)x.w);
    r.u[4] = f2bf((float)y.x); r.u[5] = f2bf((float)y.y);
    r.u[6] = f2bf((float)y.z); r.u[7] = f2bf((float)y.w);
    *(uint4*)(o + i) = r.v;
  }
}

// ---------- pass 2: 256x256 tile, BK=32, fine 2-phase schedule per K-tile ----
// Layout/swizzle/staging identical to the verified round-2 kernel (0 bank
// conflicts). Schedule: per K-tile tk (buf tk&3), two phases:
//   phase 0: ds_read aF[0..3]+bF[0..3] (8xb128) | stage piece 2tk+5 (2 gl_lds)
//            | barrier | lgkmcnt(0) | 16 MFMA (m0-3 x n0-3) | barrier
//   phase 1: ds_read aF[4..7] (4xb128)          | stage piece 2tk+6
//            | barrier | lgkmcnt(0) | 16 MFMA (m4-7 x n0-3) | vmcnt(6) | barrier
// Piece stream: piece sp = (tile sp>>1, A/B sp&1), 2 loads each, staged 5
// pieces ahead; vmcnt(6) at tile end leaves pieces 2tk+4..2tk+6 in flight and
// guarantees tile tk+1 resident (in-order vmem retirement). Piece 2tk+6 goes
// to buf (tk+3)&3 = buf of tile tk-1, freed at the end-of-tk-1 barrier.
__global__ __launch_bounds__(512, 2) void gemm_bf16_pipe(
    const unsigned short* __restrict__ Ab, const unsigned short* __restrict__ Wb,
    const float* __restrict__ sc, const float* __restrict__ bi,
    float* __restrict__ out) {
  __shared__ unsigned short sm[4][2][8192];  // [buf][A/B][256 rows x 32 k]
  const int tid = threadIdx.x;
  const int lane = tid & 63;
  const int wv = tid >> 6;
  const int wv5 = wv * 512;
  // XCD-aware swizzle: 2048 blocks % 8 == 0
  const int wg = (blockIdx.x & 7) * 256 + (blockIdx.x >> 3);
  const int bm = (wg & 31) * 256;  // M/256 = 32; consecutive wg share B-panel
  const int bn = (wg >> 5) * 256;  // N/256 = 64
  const int wr = wv >> 2;          // 0..1 -> rows wr*128..+128
  const int wc = wv & 3;           // 0..3 -> cols wc*64..+64
  const int r16 = lane & 15;
  const int g4 = lane >> 4;

  // staging source (pre-swizzled k-slot so swizzled ds_read recovers (row,k))
  const int ksl8 = (((tid & 3) ^ ((tid >> 3) & 3)) << 3);
  const unsigned short* aSrc = Ab + (long long)(bm + (tid >> 2)) * KDIM + ksl8;
  const unsigned short* bSrc = Wb + (long long)(bn + (tid >> 2)) * KDIM + ksl8;

  // tile-invariant swizzled frag offsets (ushort units)
  int aOff[8], bOff[4];
#pragma unroll
  for (int m = 0; m < 8; ++m) {
    const int row = wr * 128 + m * 16 + r16;
    aOff[m] = row * 32 + ((g4 ^ ((row >> 1) & 3)) << 3);
  }
#pragma unroll
  for (int n = 0; n < 4; ++n) {
    const int row = wc * 64 + n * 16 + r16;
    bOff[n] = row * 32 + ((g4 ^ ((row >> 1) & 3)) << 3);
  }

  f32x4 acc[8][4] = {};

  auto STAGE_PIECE = [&](int sp) {
    const int tt = sp >> 1;
    const int buf = tt & 3;
    const int kt = tt * 32;
    if ((sp & 1) == 0) {
      gload_lds16(aSrc + kt, &sm[buf][0][wv5]);
      gload_lds16(aSrc + (long long)128 * KDIM + kt, &sm[buf][0][4096 + wv5]);
    } else {
      gload_lds16(bSrc + kt, &sm[buf][1][wv5]);
      gload_lds16(bSrc + (long long)128 * KDIM + kt, &sm[buf][1][4096 + wv5]);
    }
  };

  // prologue: pieces 0..4 (tiles 0,1 + A of 2); wait tile 0 resident
  STAGE_PIECE(0);
  STAGE_PIECE(1);
  STAGE_PIECE(2);
  STAGE_PIECE(3);
  STAGE_PIECE(4);
  asm volatile("s_waitcnt vmcnt(6)" ::: "memory");
  __builtin_amdgcn_s_barrier();

  for (int tk = 0; tk < 128; ++tk) {
    const unsigned short* Al = &sm[tk & 3][0][0];
    const unsigned short* Bl = &sm[tk & 3][1][0];

    // ---------------- phase 0 ----------------
    bf16x8 aF0[4], bF[4];
#pragma unroll
    for (int m = 0; m < 4; ++m) aF0[m] = *(const bf16x8*)&Al[aOff[m]];
#pragma unroll
    for (int n = 0; n < 4; ++n) bF[n] = *(const bf16x8*)&Bl[bOff[n]];
    if (tk <= 125) STAGE_PIECE(2 * tk + 5);
    __builtin_amdgcn_s_barrier();
    asm volatile("s_waitcnt lgkmcnt(0)" ::: "memory");
    __builtin_amdgcn_sched_barrier(0);
    __builtin_amdgcn_s_setprio(1);
#pragma unroll
    for (int m = 0; m < 4; ++m)
#pragma unroll
      for (int n = 0; n < 4; ++n)
        acc[m][n] = __builtin_amdgcn_mfma_f32_16x16x32_bf16(
            aF0[m], bF[n], acc[m][n], 0, 0, 0);
    __builtin_amdgcn_s_setprio(0);
    __builtin_amdgcn_s_barrier();

    // ---------------- phase 1 ----------------
    bf16x8 aF1[4];
#pragma unroll
    for (int m = 0; m < 4; ++m) aF1[m] = *(const bf16x8*)&Al[aOff[m + 4]];
    if (tk <= 124) STAGE_PIECE(2 * tk + 6);
    __builtin_amdgcn_s_barrier();
    asm volatile("s_waitcnt lgkmcnt(0)" ::: "memory");
    __builtin_amdgcn_sched_barrier(0);
    __builtin_amdgcn_s_setprio(1);
#pragma unroll
    for (int m = 0; m < 4; ++m)
#pragma unroll
      for (int n = 0; n < 4; ++n)
        acc[m + 4][n] = __builtin_amdgcn_mfma_f32_16x16x32_bf16(
            aF1[m], bF[n], acc[m + 4][n], 0, 0, 0);
    __builtin_amdgcn_s_setprio(0);
    if (tk < 125) {
      asm volatile("s_waitcnt vmcnt(6)" ::: "memory");  // tile tk+1 resident
    } else if (tk == 125) {
      asm volatile("s_waitcnt vmcnt(4)" ::: "memory");
    } else if (tk == 126) {
      asm volatile("s_waitcnt vmcnt(0)" ::: "memory");
    }
    if (tk < 127) __builtin_amdgcn_s_barrier();
  }

  // epilogue: C/D layout col = lane&15, row = (lane>>4)*4 + r
  float sv[4], bv[4];
#pragma unroll
  for (int n = 0; n < 4; ++n) {
    const int c = bn + wc * 64 + n * 16 + r16;
    sv[n] = sc[c];
    bv[n] = bi[c];
  }
#pragma unroll
  for (int m = 0; m < 8; ++m) {
    const int row0 = bm + wr * 128 + m * 16 + g4 * 4;
#pragma unroll
    for (int n = 0; n < 4; ++n) {
      const int c = bn + wc * 64 + n * 16 + r16;
      float* op = out + (long long)row0 * NDIM + c;
#pragma unroll
      for (int r = 0; r < 4; ++r)
        op[(long long)r * NDIM] = acc[m][n][r] * sv[n] + bv[n];
    }
  }
}

// ---------- fallback: inline-convert reg-staged GEMM (if ws too small) ----------
__global__ __launch_bounds__(256, 2) void gemm_inline(
    const float* __restrict__ A, const int* __restrict__ W,
    const float* __restrict__ sc, const float* __restrict__ bi,
    float* __restrict__ out) {
  __shared__ unsigned short As[128 * 72];
  __shared__ unsigned short Bs[128 * 72];
  const int tid = threadIdx.x;
  const int lane = tid & 63;
  const int wv = tid >> 6;
  const int wg = (blockIdx.x & 7) * 1024 + (blockIdx.x >> 3);
  const int bm = (wg & 63) * 128;
  const int bn = (wg >> 6) * 128;
  const int wr = (wv >> 1) * 64;
  const int wc = (wv & 1) * 64;
  const int r16 = lane & 15;
  const int g4 = lane >> 4;

  f32x4 acc[4][4] = {};

  const int srow = tid >> 4;
  const int sc4 = (tid & 15) << 2;
  const float* aPtr = A + (long long)(bm + srow) * KDIM + sc4;
  const int* wPtr = W + (long long)(bn + srow) * KDIM + sc4;

  for (int kt = 0; kt < KDIM; kt += 64) {
    float4 av[8];
    int4 wv4[8];
#pragma unroll
    for (int j = 0; j < 8; ++j)
      av[j] = *(const float4*)(aPtr + (long long)j * 16 * KDIM + kt);
#pragma unroll
    for (int j = 0; j < 8; ++j)
      wv4[j] = *(const int4*)(wPtr + (long long)j * 16 * KDIM + kt);
    __syncthreads();
#pragma unroll
    for (int j = 0; j < 8; ++j) {
      ushort4 u;
      u.x = f2bf(av[j].x); u.y = f2bf(av[j].y);
      u.z = f2bf(av[j].z); u.w = f2bf(av[j].w);
      *(ushort4*)&As[(srow + j * 16) * 72 + sc4] = u;
    }
#pragma unroll
    for (int j = 0; j < 8; ++j) {
      ushort4 u;
      u.x = f2bf((float)wv4[j].x); u.y = f2bf((float)wv4[j].y);
      u.z = f2bf((float)wv4[j].z); u.w = f2bf((float)wv4[j].w);
      *(ushort4*)&Bs[(srow + j * 16) * 72 + sc4] = u;
    }
    __syncthreads();
#pragma unroll
    for (int ks = 0; ks < 2; ++ks) {
      bf16x8 aF[4], bF[4];
      const int kofs = ks * 32 + g4 * 8;
#pragma unroll
      for (int m2 = 0; m2 < 4; ++m2)
        aF[m2] = *(const bf16x8*)&As[(wr + m2 * 16 + r16) * 72 + kofs];
#pragma unroll
      for (int n2 = 0; n2 < 4; ++n2)
        bF[n2] = *(const bf16x8*)&Bs[(wc + n2 * 16 + r16) * 72 + kofs];
#pragma unroll
      for (int m2 = 0; m2 < 4; ++m2)
#pragma unroll
        for (int n2 = 0; n2 < 4; ++n2)
          acc[m2][n2] = __builtin_amdgcn_mfma_f32_16x16x32_bf16(
              aF[m2], bF[n2], acc[m2][n2], 0, 0, 0);
    }
  }

  float sv[4], bv[4];
#pragma unroll
  for (int n2 = 0; n2 < 4; ++n2) {
    const int c = bn + wc + n2 * 16 + r16;
    sv[n2] = sc[c];
    bv[n2] = bi[c];
  }
#pragma unroll
  for (int m2 = 0; m2 < 4; ++m2) {
    const int row0 = bm + wr + m2 * 16 + g4 * 4;
#pragma unroll
    for (int n2 = 0; n2 < 4; ++n2) {
      const int c = bn + wc + n2 * 16 + r16;
      float* op = out + (long long)row0 * NDIM + c;
#pragma unroll
      for (int r = 0; r < 4; ++r)
        op[(long long)r * NDIM] = acc[m2][n2][r] * sv[n2] + bv[n2];
    }
  }
}

extern "C" void kernel_launch(void* const* d_in, const int* in_sizes, int n_in,
                              void* d_out, int out_size, void* d_ws, size_t ws_size,
                              hipStream_t stream) {
  const float* A = (const float*)d_in[0];
  const int* W = (const int*)d_in[1];
  const float* sc = (const float*)d_in[2];
  const float* bi = (const float*)d_in[3];
  float* out = (float*)d_out;

  const long long nA = (long long)MDIM * KDIM;
  const long long nW = (long long)NDIM * KDIM;
  const size_t needA = (size_t)nA * sizeof(unsigned short);
  const size_t needW = (size_t)nW * sizeof(unsigned short);

  if (d_ws != nullptr && ws_size >= needA + needW) {
    unsigned short* Ab = (unsigned short*)d_ws;
    unsigned short* Wb = (unsigned short*)((char*)d_ws + needA);
    cvt_a_kernel<<<2048, 256, 0, stream>>>(A, Ab, nA);
    cvt_w_kernel<<<4096, 256, 0, stream>>>(W, Wb, nW);
    gemm_bf16_pipe<<<2048, 512, 0, stream>>>(Ab, Wb, sc, bi, out);
  } else {
    gemm_inline<<<8192, 256, 0, stream>>>(A, W, sc, bi, out);
  }
}